// Round 21
// baseline (215.577 us; speedup 1.0000x reference)
//
#include <hip/hip_runtime.h>
#include <hip/hip_fp16.h>
#include <hip/hip_cooperative_groups.h>
namespace cg = cooperative_groups;

#define NN 50000
#define NE 1600000
#define NG 512
#define RB 98                               // destination rows per bucket
#define NB 511                              // ceil(NN/RB); 511*98 = 50078
#define SEGCAP 512                          // records per (bucket, xcd-segment); mean 391, +6 sigma
#define CAP 72                              // padded CSR row capacity (mean 32, ~7 sigma)
#define PBLK 200                            // partition blocks; run = 8000/511 ~ 15.7 recs ~ 1 line
#define EPB (NE / PBLK)                     // 8000 edges per partition block
#define G1_BLOCKS ((NN * 16 + 511) / 512)   // 1563; 2 outputs per thread, 512-thread blocks
#define ZWORDS (NB * 8 + NG * 64)           // bcur + gpool words to zero

union H4 { uint2 u; __half2 h[2]; };        // 4 halves = 8 B

// ---------- Z: zero bcur + gpool ----------
__global__ __launch_bounds__(256) void zero_k(int* __restrict__ p) {
    int i = blockIdx.x * 256 + threadIdx.x;
    for (; i < ZWORDS; i += 64 * 256) p[i] = 0;
}

// ---------- A (512 threads): fused two-phase edge partition + layer-1 GEMM ----------
__global__ __launch_bounds__(512) void part_gemm1(const int* __restrict__ ei,
                                                  int* __restrict__ bcur,
                                                  unsigned int* __restrict__ bucket,
                                                  const float* __restrict__ x,
                                                  const float* __restrict__ w_a,
                                                  const float* __restrict__ w_b,
                                                  __half* __restrict__ y) {
    __shared__ union {
        struct {
            int lc[NB];                      // 2044 B
            unsigned short rank[EPB];        // 16000 B  (total 18044 B)
        } p;
        float Wt[64][33];                    // 8448 B
    } sm;
    int tid = threadIdx.x;
    if (blockIdx.x < PBLK) {
        int xcd = blockIdx.x & 7;
        for (int i = tid; i < NB; i += 512) sm.p.lc[i] = 0;
        __syncthreads();
        int e0 = blockIdx.x * EPB;
        const int4* row4 = reinterpret_cast<const int4*>(ei + e0);
        const int4* col4 = reinterpret_cast<const int4*>(ei + NE + e0);
        for (int i0 = tid * 4; i0 < EPB; i0 += 2048) {
            int4 r = row4[i0 >> 2];
            sm.p.rank[i0 + 0] = (unsigned short)atomicAdd(&sm.p.lc[r.x / RB], 1);
            sm.p.rank[i0 + 1] = (unsigned short)atomicAdd(&sm.p.lc[r.y / RB], 1);
            sm.p.rank[i0 + 2] = (unsigned short)atomicAdd(&sm.p.lc[r.z / RB], 1);
            sm.p.rank[i0 + 3] = (unsigned short)atomicAdd(&sm.p.lc[r.w / RB], 1);
        }
        __syncthreads();
        if (tid < NB) sm.p.lc[tid] = atomicAdd(&bcur[tid * 8 + xcd], sm.p.lc[tid]);
        __syncthreads();
        for (int i0 = tid * 4; i0 < EPB; i0 += 2048) {
            int4 r = row4[i0 >> 2];
            int4 c = col4[i0 >> 2];
#pragma unroll
            for (int j = 0; j < 4; ++j) {
                int row = (j == 0) ? r.x : (j == 1) ? r.y : (j == 2) ? r.z : r.w;
                int col = (j == 0) ? c.x : (j == 1) ? c.y : (j == 2) ? c.z : c.w;
                int g = row / RB, lr = row - g * RB;
                int pos = sm.p.lc[g] + (int)sm.p.rank[i0 + j];
                if (pos < SEGCAP)
                    bucket[(g * 8 + xcd) * SEGCAP + pos] = ((unsigned)lr << 16) | (unsigned)col;
            }
        }
    } else {
        for (int i = tid; i < 16 * 64; i += 512) {
            sm.Wt[i & 63][i >> 6] = w_a[i];
            sm.Wt[i & 63][16 + (i >> 6)] = w_b[i];
        }
        __syncthreads();
        int idx = (blockIdx.x - PBLK) * 512 + tid;   // [0, NN*16)
        if (idx < NN * 16) {
            int n = idx >> 4, q = idx & 15;
            const float4* xr = reinterpret_cast<const float4*>(x + n * 64);
            float acc0 = 0.f, acc1 = 0.f;
#pragma unroll
            for (int k4 = 0; k4 < 16; ++k4) {
                float4 a = xr[k4];
                acc0 += a.x * sm.Wt[4 * k4 + 0][q] + a.y * sm.Wt[4 * k4 + 1][q] +
                        a.z * sm.Wt[4 * k4 + 2][q] + a.w * sm.Wt[4 * k4 + 3][q];
                acc1 += a.x * sm.Wt[4 * k4 + 0][q + 16] + a.y * sm.Wt[4 * k4 + 1][q + 16] +
                        a.z * sm.Wt[4 * k4 + 2][q + 16] + a.w * sm.Wt[4 * k4 + 3][q + 16];
            }
            y[n * 32 + q] = __float2half_rn(acc0);
            y[n * 32 + q + 16] = __float2half_rn(acc1);
        }
    }
}

// ---------- BCD (cooperative, 511 x 512): fill slab + gather1 -> grid sync -> gather2+gemm2+pool ----------
// The slab (per-block neighbor lists) stays resident in LDS across the grid sync,
// eliminating the cols/deg global round-trip entirely.
__global__ __launch_bounds__(512) void fuse_bcd(const int* __restrict__ bcur,
                                                const unsigned int* __restrict__ bucket,
                                                const __half* __restrict__ y,
                                                __half* __restrict__ h,
                                                const float* __restrict__ w_a,
                                                const float* __restrict__ w_b,
                                                const int* __restrict__ batch,
                                                float* __restrict__ gpool) {
    __shared__ __align__(16) unsigned short slab[RB * CAP];  // 14112 B
    __shared__ int cur[RB];
    __shared__ int scnt[8];
    __shared__ float U[64][33];                              // 8448 B
    __shared__ float W2[64][17];                             // 4352 B
    __shared__ int bl[64];
    int tid = threadIdx.x, b = blockIdx.x;
    for (int i = tid; i < 32 * 16; i += 512) W2[i >> 4][i & 15] = w_a[i];
    for (int i = tid; i < 32 * 16; i += 512) W2[32 + (i >> 4)][i & 15] = w_b[i];
    if (tid < RB) cur[tid] = 0;
    if (tid >= 128 && tid < 136) scnt[tid - 128] = min(bcur[b * 8 + (tid - 128)], SEGCAP);
    __syncthreads();
    // phase A: fill slab (flattened 4096-slot space, uint4 reads)
    const uint4* bseg = reinterpret_cast<const uint4*>(bucket + (size_t)b * 8 * SEGCAP);
#pragma unroll
    for (int k = 0; k < 2; ++k) {
        int f = tid * 4 + k * 2048;
        int seg = f >> 9, pos = f & 511;
        int cnt = scnt[seg];
        if (pos >= cnt) continue;
        uint4 v4 = bseg[f >> 2];
        int lim = cnt - pos;
        { unsigned v = v4.x; int lr = v >> 16; int p = atomicAdd(&cur[lr], 1); if (p < CAP) slab[lr * CAP + p] = (unsigned short)(v & 0xffffu); }
        if (lim > 1) { unsigned v = v4.y; int lr = v >> 16; int p = atomicAdd(&cur[lr], 1); if (p < CAP) slab[lr * CAP + p] = (unsigned short)(v & 0xffffu); }
        if (lim > 2) { unsigned v = v4.z; int lr = v >> 16; int p = atomicAdd(&cur[lr], 1); if (p < CAP) slab[lr * CAP + p] = (unsigned short)(v & 0xffffu); }
        if (lim > 3) { unsigned v = v4.w; int lr = v >> 16; int p = atomicAdd(&cur[lr], 1); if (p < CAP) slab[lr * CAP + p] = (unsigned short)(v & 0xffffu); }
    }
    __syncthreads();
    if (tid < RB) cur[tid] = min(cur[tid], CAP);
    __syncthreads();
    // phase B: layer-1 gather y -> h (8 lanes/node)
    const uint2* y2 = reinterpret_cast<const uint2*>(y);
#pragma unroll 1
    for (int rp = 0; rp < 2; ++rp) {
        int r = rp * 64 + (tid >> 3);
        if (r >= RB) continue;
        int n = b * RB + r;
        if (n >= NN) continue;
        int d = cur[r], g = tid & 7;
        const unsigned short* c = &slab[r * CAP];
        float acc[4] = {0.f, 0.f, 0.f, 0.f};
        int i = 0;
        for (; i + 3 < d; i += 4) {
            H4 v0, v1, v2, v3;
            v0.u = y2[(int)c[i] * 8 + g];
            v1.u = y2[(int)c[i + 1] * 8 + g];
            v2.u = y2[(int)c[i + 2] * 8 + g];
            v3.u = y2[(int)c[i + 3] * 8 + g];
#pragma unroll
            for (int j = 0; j < 2; ++j) {
                float2 f0 = __half22float2(v0.h[j]);
                float2 f1 = __half22float2(v1.h[j]);
                float2 f2 = __half22float2(v2.h[j]);
                float2 f3 = __half22float2(v3.h[j]);
                acc[2 * j] += (f0.x + f1.x) + (f2.x + f3.x);
                acc[2 * j + 1] += (f0.y + f1.y) + (f2.y + f3.y);
            }
        }
        for (; i < d; ++i) {
            H4 v0;
            v0.u = y2[(int)c[i] * 8 + g];
#pragma unroll
            for (int j = 0; j < 2; ++j) {
                float2 f0 = __half22float2(v0.h[j]);
                acc[2 * j] += f0.x;
                acc[2 * j + 1] += f0.y;
            }
        }
        H4 o;
#pragma unroll
        for (int j = 0; j < 2; ++j) {
            float2 f = {fmaxf(acc[2 * j], 0.f), fmaxf(acc[2 * j + 1], 0.f)};
            o.h[j] = __float22half2_rn(f);
        }
        reinterpret_cast<uint2*>(h)[n * 8 + g] = o.u;
    }
    __threadfence();
    cg::this_grid().sync();
    // phase C: layer-2 gather (cols from LDS slab) + GEMM2 + in-register pool
    const uint2* h2 = reinterpret_cast<const uint2*>(h);
#pragma unroll 1
    for (int rp = 0; rp < 2; ++rp) {
        __syncthreads();                     // previous chunk's epilogue done
        int rbase = rp * 64;
        int rows = min(64, RB - rbase);      // 64 then 34
        if (tid < 64) {
            int nn = b * RB + rbase + tid;
            bl[tid] = (tid < rows && nn < NN) ? batch[nn] : -1;
        }
        int rl = tid >> 3, g = tid & 7;
        int r = rbase + rl;
        int n = b * RB + r;
        float acc[4] = {0.f, 0.f, 0.f, 0.f};
        if (r < RB && n < NN) {
            int d = cur[r];
            const unsigned short* c = &slab[r * CAP];
            int i = 0;
            for (; i + 3 < d; i += 4) {
                H4 v0, v1, v2, v3;
                v0.u = h2[(int)c[i] * 8 + g];
                v1.u = h2[(int)c[i + 1] * 8 + g];
                v2.u = h2[(int)c[i + 2] * 8 + g];
                v3.u = h2[(int)c[i + 3] * 8 + g];
#pragma unroll
                for (int j = 0; j < 2; ++j) {
                    float2 f0 = __half22float2(v0.h[j]);
                    float2 f1 = __half22float2(v1.h[j]);
                    float2 f2 = __half22float2(v2.h[j]);
                    float2 f3 = __half22float2(v3.h[j]);
                    acc[2 * j] += (f0.x + f1.x) + (f2.x + f3.x);
                    acc[2 * j + 1] += (f0.y + f1.y) + (f2.y + f3.y);
                }
            }
            for (; i < d; ++i) {
                H4 v0;
                v0.u = h2[(int)c[i] * 8 + g];
#pragma unroll
                for (int j = 0; j < 2; ++j) {
                    float2 f0 = __half22float2(v0.h[j]);
                    acc[2 * j] += f0.x;
                    acc[2 * j + 1] += f0.y;
                }
            }
        }
#pragma unroll
        for (int j = 0; j < 4; ++j) U[rl][g * 4 + j] = acc[j];
        __syncthreads();
        // GEMM2 + pool: 8 walkers x 64 outputs over this chunk's rows
        int o = tid & 63, w = tid >> 6;
        int ub = (o < 32) ? 0 : 16;
        int curg = -1;
        float sum = 0.f;
#pragma unroll 1
        for (int r2 = w; r2 < rows; r2 += 8) {
            int nn = b * RB + rbase + r2;
            if (nn >= NN) break;
            float a = 0.f;
#pragma unroll
            for (int k = 0; k < 16; ++k) a += U[r2][ub + k] * W2[o][k];
            a = fmaxf(a, 0.f);
            int gb = bl[r2];
            if (gb != curg) {
                if (curg >= 0) atomicAdd(&gpool[curg * 64 + o], sum);
                curg = gb;
                sum = a;
            } else {
                sum += a;
            }
        }
        if (curg >= 0) atomicAdd(&gpool[curg * 64 + o], sum);
    }
}

// ---------- E: per-graph mean + 64->128 relu MLP + 128->1 ----------
__global__ __launch_bounds__(128) void mlp_k(const float* __restrict__ gpool,
                                             const int* __restrict__ batch,
                                             const float* __restrict__ fc1_w,
                                             const float* __restrict__ fc1_b,
                                             const float* __restrict__ fc2_w,
                                             const float* __restrict__ fc2_b,
                                             float* __restrict__ out) {
    int b = blockIdx.x, tid = threadIdx.x;
    int lo = 0, hi = NN;
    while (lo < hi) { int m = (lo + hi) >> 1; if (batch[m] < b) lo = m + 1; else hi = m; }
    int start = lo;
    lo = start; hi = NN;
    while (lo < hi) { int m = (lo + hi) >> 1; if (batch[m] < b + 1) lo = m + 1; else hi = m; }
    int end = lo;
    float inv = 1.f / (float)max(end - start, 1);

    __shared__ float gvec[64];
    if (tid < 64) gvec[tid] = gpool[b * 64 + tid] * inv;
    __syncthreads();

    float hj = fc1_b[tid];
    const float* w = fc1_w + tid * 64;
#pragma unroll
    for (int k = 0; k < 64; ++k) hj += gvec[k] * w[k];
    hj = fmaxf(hj, 0.f);
    __shared__ float red[128];
    red[tid] = hj * fc2_w[tid];
    __syncthreads();
    for (int s = 64; s > 0; s >>= 1) {
        if (tid < s) red[tid] += red[tid + s];
        __syncthreads();
    }
    if (tid == 0) out[b] = red[0] + fc2_b[0];
}

static inline size_t align256(size_t v) { return (v + 255) & ~(size_t)255; }

extern "C" void kernel_launch(void* const* d_in, const int* in_sizes, int n_in,
                              void* d_out, int out_size, void* d_ws, size_t ws_size,
                              hipStream_t stream) {
    const float* x      = (const float*)d_in[0];
    const int*   ei     = (const int*)d_in[1];
    const int*   batch  = (const int*)d_in[3];
    const float* c1_fc  = (const float*)d_in[4];
    const float* c2_fc  = (const float*)d_in[7];
    const float* c1e_fc = (const float*)d_in[10];
    const float* c2e_fc = (const float*)d_in[13];
    const float* fc1_w  = (const float*)d_in[16];
    const float* fc1_b  = (const float*)d_in[17];
    const float* fc2_w  = (const float*)d_in[18];
    const float* fc2_b  = (const float*)d_in[19];
    float* out = (float*)d_out;

    char* base = (char*)d_ws;
    size_t off = 0;
    int* bcur            = (int*)(base + off);            off += sizeof(int) * NB * 8;
    float* gpool         = (float*)(base + off);          off += sizeof(float) * NG * 64;
    off = align256(off);
    unsigned int* bucket = (unsigned int*)(base + off);   off += sizeof(unsigned int) * (size_t)NB * 8 * SEGCAP;
    off = align256(off);
    __half* y            = (__half*)(base + off);         off += sizeof(__half) * (size_t)NN * 32;
    off = align256(off);
    __half* h            = (__half*)(base + off);         off += sizeof(__half) * (size_t)NN * 32;

    zero_k<<<64, 256, 0, stream>>>(bcur);  // bcur + gpool contiguous
    part_gemm1<<<PBLK + G1_BLOCKS, 512, 0, stream>>>(ei, bcur, bucket, x, c1_fc, c1e_fc, y);
    {
        void* args[] = {(void*)&bcur, (void*)&bucket, (void*)&y, (void*)&h,
                        (void*)&c2_fc, (void*)&c2e_fc, (void*)&batch, (void*)&gpool};
        hipLaunchCooperativeKernel((const void*)fuse_bcd, dim3(NB), dim3(512), args, 0, stream);
    }
    mlp_k<<<NG, 128, 0, stream>>>(gpool, batch, fc1_w, fc1_b, fc2_w, fc2_b, out);
}

// Round 22
// 82.528 us; speedup vs baseline: 2.6122x; 2.6122x over previous
//
#include <hip/hip_runtime.h>
#include <hip/hip_fp16.h>

#define NN 50000
#define NE 1600000
#define NG 512
#define RB 98                               // destination rows per bucket
#define NB 511                              // ceil(NN/RB); 511*98 = 50078
#define NNP (NB * RB)                       // padded node count
#define SEGCAP 512                          // records per (bucket, xcd-segment); mean 391, +6 sigma
#define CAP 72                              // padded CSR row capacity (mean 32, ~7 sigma)
#define PBLK 200                            // partition blocks; run = 8000/511 ~ 15.7 recs ~ 1 line
#define EPB (NE / PBLK)                     // 8000 edges per partition block
#define G1_BLOCKS ((NN * 16 + 1023) / 1024) // 782; 2 outputs per thread, 1024-thread blocks
#define ZWORDS (NB * 8 + NG * 64)           // bcur + gpool words to zero

union H4 { uint2 u; __half2 h[2]; };        // 4 halves = 8 B

// ---------- Z: zero bcur + gpool ----------
__global__ __launch_bounds__(256) void zero_k(int* __restrict__ p) {
    int i = blockIdx.x * 256 + threadIdx.x;
    for (; i < ZWORDS; i += 64 * 256) p[i] = 0;
}

// ---------- A (1024 threads): fused two-phase edge partition + layer-1 GEMM ----------
// 1024 threads/block -> 16 waves: 4 waves/SIMD in the partition tail phase
// (200 blocks alone on the machine after gemm1 blocks drain). Memory traffic unchanged.
__global__ __launch_bounds__(1024) void part_gemm1(const int* __restrict__ ei,
                                                   int* __restrict__ bcur,
                                                   unsigned int* __restrict__ bucket,
                                                   const float* __restrict__ x,
                                                   const float* __restrict__ w_a,
                                                   const float* __restrict__ w_b,
                                                   __half* __restrict__ y) {
    __shared__ union {
        struct {
            int lc[NB];                      // 2044 B
            unsigned short rank[EPB];        // 16000 B  (total 18044 B)
        } p;
        float Wt[64][33];                    // 8448 B
    } sm;
    int tid = threadIdx.x;
    if (blockIdx.x < PBLK) {
        int xcd = blockIdx.x & 7;
        for (int i = tid; i < NB; i += 1024) sm.p.lc[i] = 0;
        __syncthreads();
        int e0 = blockIdx.x * EPB;
        const int4* row4 = reinterpret_cast<const int4*>(ei + e0);
        const int4* col4 = reinterpret_cast<const int4*>(ei + NE + e0);
        for (int i0 = tid * 4; i0 < EPB; i0 += 4096) {
            int4 r = row4[i0 >> 2];
            sm.p.rank[i0 + 0] = (unsigned short)atomicAdd(&sm.p.lc[r.x / RB], 1);
            sm.p.rank[i0 + 1] = (unsigned short)atomicAdd(&sm.p.lc[r.y / RB], 1);
            sm.p.rank[i0 + 2] = (unsigned short)atomicAdd(&sm.p.lc[r.z / RB], 1);
            sm.p.rank[i0 + 3] = (unsigned short)atomicAdd(&sm.p.lc[r.w / RB], 1);
        }
        __syncthreads();
        if (tid < NB) sm.p.lc[tid] = atomicAdd(&bcur[tid * 8 + xcd], sm.p.lc[tid]);
        __syncthreads();
        for (int i0 = tid * 4; i0 < EPB; i0 += 4096) {
            int4 r = row4[i0 >> 2];
            int4 c = col4[i0 >> 2];
#pragma unroll
            for (int j = 0; j < 4; ++j) {
                int row = (j == 0) ? r.x : (j == 1) ? r.y : (j == 2) ? r.z : r.w;
                int col = (j == 0) ? c.x : (j == 1) ? c.y : (j == 2) ? c.z : c.w;
                int g = row / RB, lr = row - g * RB;
                int pos = sm.p.lc[g] + (int)sm.p.rank[i0 + j];
                if (pos < SEGCAP)
                    bucket[(g * 8 + xcd) * SEGCAP + pos] = ((unsigned)lr << 16) | (unsigned)col;
            }
        }
    } else {
        for (int i = tid; i < 16 * 64; i += 1024) {
            sm.Wt[i & 63][i >> 6] = w_a[i];
            sm.Wt[i & 63][16 + (i >> 6)] = w_b[i];
        }
        __syncthreads();
        int idx = (blockIdx.x - PBLK) * 1024 + tid;  // [0, NN*16)
        if (idx < NN * 16) {
            int n = idx >> 4, q = idx & 15;
            const float4* xr = reinterpret_cast<const float4*>(x + n * 64);
            float acc0 = 0.f, acc1 = 0.f;
#pragma unroll
            for (int k4 = 0; k4 < 16; ++k4) {
                float4 a = xr[k4];
                acc0 += a.x * sm.Wt[4 * k4 + 0][q] + a.y * sm.Wt[4 * k4 + 1][q] +
                        a.z * sm.Wt[4 * k4 + 2][q] + a.w * sm.Wt[4 * k4 + 3][q];
                acc1 += a.x * sm.Wt[4 * k4 + 0][q + 16] + a.y * sm.Wt[4 * k4 + 1][q + 16] +
                        a.z * sm.Wt[4 * k4 + 2][q + 16] + a.w * sm.Wt[4 * k4 + 3][q + 16];
            }
            y[n * 32 + q] = __float2half_rn(acc0);
            y[n * 32 + q + 16] = __float2half_rn(acc1);
        }
    }
}

// ---------- B+C fused (512 threads): flattened fill + cols/deg + gather layer-1 (8 lanes/node) ----------
__global__ __launch_bounds__(512) void fillgather1(const int* __restrict__ bcur,
                                                   const unsigned int* __restrict__ bucket,
                                                   int* __restrict__ deg,
                                                   unsigned short* __restrict__ cols,
                                                   const __half* __restrict__ y,
                                                   __half* __restrict__ h) {
    __shared__ __align__(16) unsigned short slab[RB * CAP];  // 14112 B
    __shared__ int cur[RB];
    __shared__ int scnt[8];
    int tid = threadIdx.x, b = blockIdx.x;
    if (tid < RB) cur[tid] = 0;
    if (tid >= 128 && tid < 136) scnt[tid - 128] = min(bcur[b * 8 + (tid - 128)], SEGCAP);
    __syncthreads();
    const uint4* bseg = reinterpret_cast<const uint4*>(bucket + (size_t)b * 8 * SEGCAP);
#pragma unroll
    for (int k = 0; k < 2; ++k) {
        int f = tid * 4 + k * 2048;          // [0, 4096)
        int seg = f >> 9, pos = f & 511;
        int cnt = scnt[seg];
        if (pos >= cnt) continue;
        uint4 v4 = bseg[f >> 2];
        int lim = cnt - pos;                 // >= 1
        {
            unsigned v = v4.x; int lr = v >> 16;
            int p = atomicAdd(&cur[lr], 1);
            if (p < CAP) slab[lr * CAP + p] = (unsigned short)(v & 0xffffu);
        }
        if (lim > 1) {
            unsigned v = v4.y; int lr = v >> 16;
            int p = atomicAdd(&cur[lr], 1);
            if (p < CAP) slab[lr * CAP + p] = (unsigned short)(v & 0xffffu);
        }
        if (lim > 2) {
            unsigned v = v4.z; int lr = v >> 16;
            int p = atomicAdd(&cur[lr], 1);
            if (p < CAP) slab[lr * CAP + p] = (unsigned short)(v & 0xffffu);
        }
        if (lim > 3) {
            unsigned v = v4.w; int lr = v >> 16;
            int p = atomicAdd(&cur[lr], 1);
            if (p < CAP) slab[lr * CAP + p] = (unsigned short)(v & 0xffffu);
        }
    }
    __syncthreads();
    if (tid < RB) {
        int d = min(cur[tid], CAP);
        cur[tid] = d;
        deg[b * RB + tid] = d;
    }
    {
        const uint4* src = reinterpret_cast<const uint4*>(slab);
        uint4* dst = reinterpret_cast<uint4*>(cols) + (size_t)b * (RB * CAP / 8);
        for (int i = tid; i < RB * CAP / 8; i += 512) dst[i] = src[i];
    }
    __syncthreads();
    const uint2* y2 = reinterpret_cast<const uint2*>(y);   // row n = 8 uint2
#pragma unroll 1
    for (int rp = 0; rp < 2; ++rp) {
        int r = rp * 64 + (tid >> 3);
        if (r >= RB) continue;
        int n = b * RB + r;
        if (n >= NN) continue;
        int d = cur[r], g = tid & 7;
        const unsigned short* c = &slab[r * CAP];
        float acc[4] = {0.f, 0.f, 0.f, 0.f};
        int i = 0;
        for (; i + 3 < d; i += 4) {
            H4 v0, v1, v2, v3;
            v0.u = y2[(int)c[i] * 8 + g];
            v1.u = y2[(int)c[i + 1] * 8 + g];
            v2.u = y2[(int)c[i + 2] * 8 + g];
            v3.u = y2[(int)c[i + 3] * 8 + g];
#pragma unroll
            for (int j = 0; j < 2; ++j) {
                float2 f0 = __half22float2(v0.h[j]);
                float2 f1 = __half22float2(v1.h[j]);
                float2 f2 = __half22float2(v2.h[j]);
                float2 f3 = __half22float2(v3.h[j]);
                acc[2 * j] += (f0.x + f1.x) + (f2.x + f3.x);
                acc[2 * j + 1] += (f0.y + f1.y) + (f2.y + f3.y);
            }
        }
        for (; i < d; ++i) {
            H4 v0;
            v0.u = y2[(int)c[i] * 8 + g];
#pragma unroll
            for (int j = 0; j < 2; ++j) {
                float2 f0 = __half22float2(v0.h[j]);
                acc[2 * j] += f0.x;
                acc[2 * j + 1] += f0.y;
            }
        }
        H4 o;
#pragma unroll
        for (int j = 0; j < 2; ++j) {
            float2 f = {fmaxf(acc[2 * j], 0.f), fmaxf(acc[2 * j + 1], 0.f)};
            o.h[j] = __float22half2_rn(f);
        }
        reinterpret_cast<uint2*>(h)[n * 8 + g] = o.u;
    }
}

// ---------- D (512 threads): layer-2 gather (8 lanes/node) + GEMM2 + in-register pool ----------
__global__ __launch_bounds__(512) void gatherD(const int* __restrict__ deg,
                                               const unsigned short* __restrict__ cols,
                                               const __half* __restrict__ h,
                                               const float* __restrict__ w_a,
                                               const float* __restrict__ w_b,
                                               const int* __restrict__ batch,
                                               float* __restrict__ gpool) {
    __shared__ float U[64][33];
    __shared__ float W2[64][17];
    __shared__ int bl[64];
    int tid = threadIdx.x;
    int n0 = blockIdx.x * 64;
    for (int i = tid; i < 32 * 16; i += 512) W2[i >> 4][i & 15] = w_a[i];
    for (int i = tid; i < 32 * 16; i += 512) W2[32 + (i >> 4)][i & 15] = w_b[i];
    if (tid < 64) bl[tid] = (n0 + tid < NN) ? batch[n0 + tid] : -1;
    int nl = tid >> 3, g = tid & 7;
    int n = n0 + nl;
    float acc[4] = {0.f, 0.f, 0.f, 0.f};
    if (n < NN) {
        int d = deg[n];
        const unsigned short* cs = cols + (size_t)n * CAP;
        const unsigned int* cp = reinterpret_cast<const unsigned int*>(cs);
        const uint2* h2 = reinterpret_cast<const uint2*>(h);
        int i = 0;
        for (; i + 3 < d; i += 4) {
            unsigned int cc0 = cp[i >> 1], cc1 = cp[(i >> 1) + 1];
            H4 v0, v1, v2, v3;
            v0.u = h2[(cc0 & 0xffffu) * 8 + g];
            v1.u = h2[(cc0 >> 16) * 8 + g];
            v2.u = h2[(cc1 & 0xffffu) * 8 + g];
            v3.u = h2[(cc1 >> 16) * 8 + g];
#pragma unroll
            for (int j = 0; j < 2; ++j) {
                float2 f0 = __half22float2(v0.h[j]);
                float2 f1 = __half22float2(v1.h[j]);
                float2 f2 = __half22float2(v2.h[j]);
                float2 f3 = __half22float2(v3.h[j]);
                acc[2 * j] += (f0.x + f1.x) + (f2.x + f3.x);
                acc[2 * j + 1] += (f0.y + f1.y) + (f2.y + f3.y);
            }
        }
        for (; i < d; ++i) {
            H4 v0;
            v0.u = h2[(int)cs[i] * 8 + g];
#pragma unroll
            for (int j = 0; j < 2; ++j) {
                float2 f0 = __half22float2(v0.h[j]);
                acc[2 * j] += f0.x;
                acc[2 * j + 1] += f0.y;
            }
        }
    }
#pragma unroll
    for (int j = 0; j < 4; ++j) U[nl][g * 4 + j] = acc[j];
    __syncthreads();
    int o = tid & 63, w = tid >> 6;
    int ub = (o < 32) ? 0 : 16;
    int curg = -1;
    float sum = 0.f;
#pragma unroll 1
    for (int r = w; r < 64; r += 8) {
        if (n0 + r >= NN) break;
        float a = 0.f;
#pragma unroll
        for (int k = 0; k < 16; ++k) a += U[r][ub + k] * W2[o][k];
        a = fmaxf(a, 0.f);
        int gb = bl[r];
        if (gb != curg) {
            if (curg >= 0) atomicAdd(&gpool[curg * 64 + o], sum);
            curg = gb;
            sum = a;
        } else {
            sum += a;
        }
    }
    if (curg >= 0) atomicAdd(&gpool[curg * 64 + o], sum);
}

// ---------- E: per-graph mean + 64->128 relu MLP + 128->1 ----------
__global__ __launch_bounds__(128) void mlp_k(const float* __restrict__ gpool,
                                             const int* __restrict__ batch,
                                             const float* __restrict__ fc1_w,
                                             const float* __restrict__ fc1_b,
                                             const float* __restrict__ fc2_w,
                                             const float* __restrict__ fc2_b,
                                             float* __restrict__ out) {
    int b = blockIdx.x, tid = threadIdx.x;
    int lo = 0, hi = NN;
    while (lo < hi) { int m = (lo + hi) >> 1; if (batch[m] < b) lo = m + 1; else hi = m; }
    int start = lo;
    lo = start; hi = NN;
    while (lo < hi) { int m = (lo + hi) >> 1; if (batch[m] < b + 1) lo = m + 1; else hi = m; }
    int end = lo;
    float inv = 1.f / (float)max(end - start, 1);

    __shared__ float gvec[64];
    if (tid < 64) gvec[tid] = gpool[b * 64 + tid] * inv;
    __syncthreads();

    float hj = fc1_b[tid];
    const float* w = fc1_w + tid * 64;
#pragma unroll
    for (int k = 0; k < 64; ++k) hj += gvec[k] * w[k];
    hj = fmaxf(hj, 0.f);
    __shared__ float red[128];
    red[tid] = hj * fc2_w[tid];
    __syncthreads();
    for (int s = 64; s > 0; s >>= 1) {
        if (tid < s) red[tid] += red[tid + s];
        __syncthreads();
    }
    if (tid == 0) out[b] = red[0] + fc2_b[0];
}

static inline size_t align256(size_t v) { return (v + 255) & ~(size_t)255; }

extern "C" void kernel_launch(void* const* d_in, const int* in_sizes, int n_in,
                              void* d_out, int out_size, void* d_ws, size_t ws_size,
                              hipStream_t stream) {
    const float* x      = (const float*)d_in[0];
    const int*   ei     = (const int*)d_in[1];
    const int*   batch  = (const int*)d_in[3];
    const float* c1_fc  = (const float*)d_in[4];
    const float* c2_fc  = (const float*)d_in[7];
    const float* c1e_fc = (const float*)d_in[10];
    const float* c2e_fc = (const float*)d_in[13];
    const float* fc1_w  = (const float*)d_in[16];
    const float* fc1_b  = (const float*)d_in[17];
    const float* fc2_w  = (const float*)d_in[18];
    const float* fc2_b  = (const float*)d_in[19];
    float* out = (float*)d_out;

    char* base = (char*)d_ws;
    size_t off = 0;
    int* bcur            = (int*)(base + off);            off += sizeof(int) * NB * 8;
    float* gpool         = (float*)(base + off);          off += sizeof(float) * NG * 64;
    off = align256(off);
    unsigned int* bucket = (unsigned int*)(base + off);   off += sizeof(unsigned int) * (size_t)NB * 8 * SEGCAP;
    off = align256(off);
    unsigned short* cols = (unsigned short*)(base + off); off += sizeof(unsigned short) * (size_t)NNP * CAP;
    off = align256(off);
    int* deg             = (int*)(base + off);            off += sizeof(int) * NNP;
    off = align256(off);
    __half* y            = (__half*)(base + off);         off += sizeof(__half) * (size_t)NN * 32;
    off = align256(off);
    __half* h            = (__half*)(base + off);         off += sizeof(__half) * (size_t)NN * 32;

    zero_k<<<64, 256, 0, stream>>>(bcur);  // bcur + gpool contiguous
    part_gemm1<<<PBLK + G1_BLOCKS, 1024, 0, stream>>>(ei, bcur, bucket, x, c1_fc, c1e_fc, y);
    fillgather1<<<NB, 512, 0, stream>>>(bcur, bucket, deg, cols, y, h);
    gatherD<<<(NN + 63) / 64, 512, 0, stream>>>(deg, cols, h, c2_fc, c2e_fc, batch, gpool);
    mlp_k<<<NG, 128, 0, stream>>>(gpool, batch, fc1_w, fc1_b, fc2_w, fc2_b, out);
}

// Round 23
// 81.507 us; speedup vs baseline: 2.6449x; 1.0125x over previous
//
#include <hip/hip_runtime.h>
#include <hip/hip_fp16.h>

#define NN 50000
#define NE 1600000
#define NG 512
#define RB 98                               // destination rows per bucket
#define NB 511                              // ceil(NN/RB); 511*98 = 50078
#define NNP (NB * RB)                       // padded node count
#define SEGCAP 512                          // records per (bucket, xcd-segment); mean 391, +6 sigma
#define CAP 72                              // padded CSR row capacity (mean 32, ~7 sigma)
#define PBLK 200                            // partition blocks; run = 8000/511 ~ 15.7 recs ~ 1 line
#define EPB (NE / PBLK)                     // 8000 edges per partition block
#define G1_BLOCKS ((NN * 16 + 511) / 512)   // 1563; 2 outputs per thread, 512-thread blocks
#define ZWORDS (NB * 8 + NG * 64)           // bcur + gpool words to zero

union H4 { uint2 u; __half2 h[2]; };        // 4 halves = 8 B

// ---------- Z: zero bcur + gpool ----------
__global__ __launch_bounds__(256) void zero_k(int* __restrict__ p) {
    int i = blockIdx.x * 256 + threadIdx.x;
    for (; i < ZWORDS; i += 64 * 256) p[i] = 0;
}

// ---------- A (512 threads): fused two-phase edge partition + layer-1 GEMM ----------
__global__ __launch_bounds__(512) void part_gemm1(const int* __restrict__ ei,
                                                  int* __restrict__ bcur,
                                                  unsigned int* __restrict__ bucket,
                                                  const float* __restrict__ x,
                                                  const float* __restrict__ w_a,
                                                  const float* __restrict__ w_b,
                                                  __half* __restrict__ y) {
    __shared__ union {
        struct {
            int lc[NB];                      // 2044 B
            unsigned short rank[EPB];        // 16000 B  (total 18044 B)
        } p;
        float Wt[64][33];                    // 8448 B
    } sm;
    int tid = threadIdx.x;
    if (blockIdx.x < PBLK) {
        int xcd = blockIdx.x & 7;
        for (int i = tid; i < NB; i += 512) sm.p.lc[i] = 0;
        __syncthreads();
        int e0 = blockIdx.x * EPB;
        const int4* row4 = reinterpret_cast<const int4*>(ei + e0);
        const int4* col4 = reinterpret_cast<const int4*>(ei + NE + e0);
        for (int i0 = tid * 4; i0 < EPB; i0 += 2048) {
            int4 r = row4[i0 >> 2];
            sm.p.rank[i0 + 0] = (unsigned short)atomicAdd(&sm.p.lc[r.x / RB], 1);
            sm.p.rank[i0 + 1] = (unsigned short)atomicAdd(&sm.p.lc[r.y / RB], 1);
            sm.p.rank[i0 + 2] = (unsigned short)atomicAdd(&sm.p.lc[r.z / RB], 1);
            sm.p.rank[i0 + 3] = (unsigned short)atomicAdd(&sm.p.lc[r.w / RB], 1);
        }
        __syncthreads();
        if (tid < NB) sm.p.lc[tid] = atomicAdd(&bcur[tid * 8 + xcd], sm.p.lc[tid]);
        __syncthreads();
        for (int i0 = tid * 4; i0 < EPB; i0 += 2048) {
            int4 r = row4[i0 >> 2];
            int4 c = col4[i0 >> 2];
#pragma unroll
            for (int j = 0; j < 4; ++j) {
                int row = (j == 0) ? r.x : (j == 1) ? r.y : (j == 2) ? r.z : r.w;
                int col = (j == 0) ? c.x : (j == 1) ? c.y : (j == 2) ? c.z : c.w;
                int g = row / RB, lr = row - g * RB;
                int pos = sm.p.lc[g] + (int)sm.p.rank[i0 + j];
                if (pos < SEGCAP)
                    bucket[(g * 8 + xcd) * SEGCAP + pos] = ((unsigned)lr << 16) | (unsigned)col;
            }
        }
    } else {
        for (int i = tid; i < 16 * 64; i += 512) {
            sm.Wt[i & 63][i >> 6] = w_a[i];
            sm.Wt[i & 63][16 + (i >> 6)] = w_b[i];
        }
        __syncthreads();
        int idx = (blockIdx.x - PBLK) * 512 + tid;   // [0, NN*16)
        if (idx < NN * 16) {
            int n = idx >> 4, q = idx & 15;
            const float4* xr = reinterpret_cast<const float4*>(x + n * 64);
            float acc0 = 0.f, acc1 = 0.f;
#pragma unroll
            for (int k4 = 0; k4 < 16; ++k4) {
                float4 a = xr[k4];
                acc0 += a.x * sm.Wt[4 * k4 + 0][q] + a.y * sm.Wt[4 * k4 + 1][q] +
                        a.z * sm.Wt[4 * k4 + 2][q] + a.w * sm.Wt[4 * k4 + 3][q];
                acc1 += a.x * sm.Wt[4 * k4 + 0][q + 16] + a.y * sm.Wt[4 * k4 + 1][q + 16] +
                        a.z * sm.Wt[4 * k4 + 2][q + 16] + a.w * sm.Wt[4 * k4 + 3][q + 16];
            }
            y[n * 32 + q] = __float2half_rn(acc0);
            y[n * 32 + q + 16] = __float2half_rn(acc1);
        }
    }
}

// ---------- B+C fused (512 threads): flattened fill + cols/deg + gather layer-1 (8 lanes/node) ----------
__global__ __launch_bounds__(512) void fillgather1(const int* __restrict__ bcur,
                                                   const unsigned int* __restrict__ bucket,
                                                   int* __restrict__ deg,
                                                   unsigned short* __restrict__ cols,
                                                   const __half* __restrict__ y,
                                                   __half* __restrict__ h) {
    __shared__ __align__(16) unsigned short slab[RB * CAP];  // 14112 B
    __shared__ int cur[RB];
    __shared__ int scnt[8];
    int tid = threadIdx.x, b = blockIdx.x;
    if (tid < RB) cur[tid] = 0;
    if (tid >= 128 && tid < 136) scnt[tid - 128] = min(bcur[b * 8 + (tid - 128)], SEGCAP);
    __syncthreads();
    const uint4* bseg = reinterpret_cast<const uint4*>(bucket + (size_t)b * 8 * SEGCAP);
#pragma unroll
    for (int k = 0; k < 2; ++k) {
        int f = tid * 4 + k * 2048;          // [0, 4096)
        int seg = f >> 9, pos = f & 511;
        int cnt = scnt[seg];
        if (pos >= cnt) continue;
        uint4 v4 = bseg[f >> 2];
        int lim = cnt - pos;                 // >= 1
        {
            unsigned v = v4.x; int lr = v >> 16;
            int p = atomicAdd(&cur[lr], 1);
            if (p < CAP) slab[lr * CAP + p] = (unsigned short)(v & 0xffffu);
        }
        if (lim > 1) {
            unsigned v = v4.y; int lr = v >> 16;
            int p = atomicAdd(&cur[lr], 1);
            if (p < CAP) slab[lr * CAP + p] = (unsigned short)(v & 0xffffu);
        }
        if (lim > 2) {
            unsigned v = v4.z; int lr = v >> 16;
            int p = atomicAdd(&cur[lr], 1);
            if (p < CAP) slab[lr * CAP + p] = (unsigned short)(v & 0xffffu);
        }
        if (lim > 3) {
            unsigned v = v4.w; int lr = v >> 16;
            int p = atomicAdd(&cur[lr], 1);
            if (p < CAP) slab[lr * CAP + p] = (unsigned short)(v & 0xffffu);
        }
    }
    __syncthreads();
    if (tid < RB) {
        int d = min(cur[tid], CAP);
        cur[tid] = d;
        deg[b * RB + tid] = d;
    }
    {
        const uint4* src = reinterpret_cast<const uint4*>(slab);
        uint4* dst = reinterpret_cast<uint4*>(cols) + (size_t)b * (RB * CAP / 8);
        for (int i = tid; i < RB * CAP / 8; i += 512) dst[i] = src[i];
    }
    __syncthreads();
    const uint2* y2 = reinterpret_cast<const uint2*>(y);   // row n = 8 uint2
#pragma unroll 1
    for (int rp = 0; rp < 2; ++rp) {
        int r = rp * 64 + (tid >> 3);
        if (r >= RB) continue;
        int n = b * RB + r;
        if (n >= NN) continue;
        int d = cur[r], g = tid & 7;
        const unsigned short* c = &slab[r * CAP];
        float acc[4] = {0.f, 0.f, 0.f, 0.f};
        int i = 0;
        for (; i + 3 < d; i += 4) {
            H4 v0, v1, v2, v3;
            v0.u = y2[(int)c[i] * 8 + g];
            v1.u = y2[(int)c[i + 1] * 8 + g];
            v2.u = y2[(int)c[i + 2] * 8 + g];
            v3.u = y2[(int)c[i + 3] * 8 + g];
#pragma unroll
            for (int j = 0; j < 2; ++j) {
                float2 f0 = __half22float2(v0.h[j]);
                float2 f1 = __half22float2(v1.h[j]);
                float2 f2 = __half22float2(v2.h[j]);
                float2 f3 = __half22float2(v3.h[j]);
                acc[2 * j] += (f0.x + f1.x) + (f2.x + f3.x);
                acc[2 * j + 1] += (f0.y + f1.y) + (f2.y + f3.y);
            }
        }
        for (; i < d; ++i) {
            H4 v0;
            v0.u = y2[(int)c[i] * 8 + g];
#pragma unroll
            for (int j = 0; j < 2; ++j) {
                float2 f0 = __half22float2(v0.h[j]);
                acc[2 * j] += f0.x;
                acc[2 * j + 1] += f0.y;
            }
        }
        H4 o;
#pragma unroll
        for (int j = 0; j < 2; ++j) {
            float2 f = {fmaxf(acc[2 * j], 0.f), fmaxf(acc[2 * j + 1], 0.f)};
            o.h[j] = __float22half2_rn(f);
        }
        reinterpret_cast<uint2*>(h)[n * 8 + g] = o.u;
    }
}

// ---------- D (512 threads): layer-2 gather (8 lanes/node) + GEMM2 + in-register pool ----------
__global__ __launch_bounds__(512) void gatherD(const int* __restrict__ deg,
                                               const unsigned short* __restrict__ cols,
                                               const __half* __restrict__ h,
                                               const float* __restrict__ w_a,
                                               const float* __restrict__ w_b,
                                               const int* __restrict__ batch,
                                               float* __restrict__ gpool) {
    __shared__ float U[64][33];
    __shared__ float W2[64][17];
    __shared__ int bl[64];
    int tid = threadIdx.x;
    int n0 = blockIdx.x * 64;
    for (int i = tid; i < 32 * 16; i += 512) W2[i >> 4][i & 15] = w_a[i];
    for (int i = tid; i < 32 * 16; i += 512) W2[32 + (i >> 4)][i & 15] = w_b[i];
    if (tid < 64) bl[tid] = (n0 + tid < NN) ? batch[n0 + tid] : -1;
    int nl = tid >> 3, g = tid & 7;
    int n = n0 + nl;
    float acc[4] = {0.f, 0.f, 0.f, 0.f};
    if (n < NN) {
        int d = deg[n];
        const unsigned short* cs = cols + (size_t)n * CAP;
        const unsigned int* cp = reinterpret_cast<const unsigned int*>(cs);
        const uint2* h2 = reinterpret_cast<const uint2*>(h);
        int i = 0;
        for (; i + 3 < d; i += 4) {
            unsigned int cc0 = cp[i >> 1], cc1 = cp[(i >> 1) + 1];
            H4 v0, v1, v2, v3;
            v0.u = h2[(cc0 & 0xffffu) * 8 + g];
            v1.u = h2[(cc0 >> 16) * 8 + g];
            v2.u = h2[(cc1 & 0xffffu) * 8 + g];
            v3.u = h2[(cc1 >> 16) * 8 + g];
#pragma unroll
            for (int j = 0; j < 2; ++j) {
                float2 f0 = __half22float2(v0.h[j]);
                float2 f1 = __half22float2(v1.h[j]);
                float2 f2 = __half22float2(v2.h[j]);
                float2 f3 = __half22float2(v3.h[j]);
                acc[2 * j] += (f0.x + f1.x) + (f2.x + f3.x);
                acc[2 * j + 1] += (f0.y + f1.y) + (f2.y + f3.y);
            }
        }
        for (; i < d; ++i) {
            H4 v0;
            v0.u = h2[(int)cs[i] * 8 + g];
#pragma unroll
            for (int j = 0; j < 2; ++j) {
                float2 f0 = __half22float2(v0.h[j]);
                acc[2 * j] += f0.x;
                acc[2 * j + 1] += f0.y;
            }
        }
    }
#pragma unroll
    for (int j = 0; j < 4; ++j) U[nl][g * 4 + j] = acc[j];
    __syncthreads();
    int o = tid & 63, w = tid >> 6;
    int ub = (o < 32) ? 0 : 16;
    int curg = -1;
    float sum = 0.f;
#pragma unroll 1
    for (int r = w; r < 64; r += 8) {
        if (n0 + r >= NN) break;
        float a = 0.f;
#pragma unroll
        for (int k = 0; k < 16; ++k) a += U[r][ub + k] * W2[o][k];
        a = fmaxf(a, 0.f);
        int gb = bl[r];
        if (gb != curg) {
            if (curg >= 0) atomicAdd(&gpool[curg * 64 + o], sum);
            curg = gb;
            sum = a;
        } else {
            sum += a;
        }
    }
    if (curg >= 0) atomicAdd(&gpool[curg * 64 + o], sum);
}

// ---------- E: per-graph mean + 64->128 relu MLP + 128->1 ----------
__global__ __launch_bounds__(128) void mlp_k(const float* __restrict__ gpool,
                                             const int* __restrict__ batch,
                                             const float* __restrict__ fc1_w,
                                             const float* __restrict__ fc1_b,
                                             const float* __restrict__ fc2_w,
                                             const float* __restrict__ fc2_b,
                                             float* __restrict__ out) {
    int b = blockIdx.x, tid = threadIdx.x;
    int lo = 0, hi = NN;
    while (lo < hi) { int m = (lo + hi) >> 1; if (batch[m] < b) lo = m + 1; else hi = m; }
    int start = lo;
    lo = start; hi = NN;
    while (lo < hi) { int m = (lo + hi) >> 1; if (batch[m] < b + 1) lo = m + 1; else hi = m; }
    int end = lo;
    float inv = 1.f / (float)max(end - start, 1);

    __shared__ float gvec[64];
    if (tid < 64) gvec[tid] = gpool[b * 64 + tid] * inv;
    __syncthreads();

    float hj = fc1_b[tid];
    const float* w = fc1_w + tid * 64;
#pragma unroll
    for (int k = 0; k < 64; ++k) hj += gvec[k] * w[k];
    hj = fmaxf(hj, 0.f);
    __shared__ float red[128];
    red[tid] = hj * fc2_w[tid];
    __syncthreads();
    for (int s = 64; s > 0; s >>= 1) {
        if (tid < s) red[tid] += red[tid + s];
        __syncthreads();
    }
    if (tid == 0) out[b] = red[0] + fc2_b[0];
}

static inline size_t align256(size_t v) { return (v + 255) & ~(size_t)255; }

extern "C" void kernel_launch(void* const* d_in, const int* in_sizes, int n_in,
                              void* d_out, int out_size, void* d_ws, size_t ws_size,
                              hipStream_t stream) {
    const float* x      = (const float*)d_in[0];
    const int*   ei     = (const int*)d_in[1];
    const int*   batch  = (const int*)d_in[3];
    const float* c1_fc  = (const float*)d_in[4];
    const float* c2_fc  = (const float*)d_in[7];
    const float* c1e_fc = (const float*)d_in[10];
    const float* c2e_fc = (const float*)d_in[13];
    const float* fc1_w  = (const float*)d_in[16];
    const float* fc1_b  = (const float*)d_in[17];
    const float* fc2_w  = (const float*)d_in[18];
    const float* fc2_b  = (const float*)d_in[19];
    float* out = (float*)d_out;

    char* base = (char*)d_ws;
    size_t off = 0;
    int* bcur            = (int*)(base + off);            off += sizeof(int) * NB * 8;
    float* gpool         = (float*)(base + off);          off += sizeof(float) * NG * 64;
    off = align256(off);
    unsigned int* bucket = (unsigned int*)(base + off);   off += sizeof(unsigned int) * (size_t)NB * 8 * SEGCAP;
    off = align256(off);
    unsigned short* cols = (unsigned short*)(base + off); off += sizeof(unsigned short) * (size_t)NNP * CAP;
    off = align256(off);
    int* deg             = (int*)(base + off);            off += sizeof(int) * NNP;
    off = align256(off);
    __half* y            = (__half*)(base + off);         off += sizeof(__half) * (size_t)NN * 32;
    off = align256(off);
    __half* h            = (__half*)(base + off);         off += sizeof(__half) * (size_t)NN * 32;

    zero_k<<<64, 256, 0, stream>>>(bcur);  // bcur + gpool contiguous
    part_gemm1<<<PBLK + G1_BLOCKS, 512, 0, stream>>>(ei, bcur, bucket, x, c1_fc, c1e_fc, y);
    fillgather1<<<NB, 512, 0, stream>>>(bcur, bucket, deg, cols, y, h);
    gatherD<<<(NN + 63) / 64, 512, 0, stream>>>(deg, cols, h, c2_fc, c2e_fc, batch, gpool);
    mlp_k<<<NG, 128, 0, stream>>>(gpool, batch, fc1_w, fc1_b, fc2_w, fc2_b, out);
}